// Round 10
// baseline (182.963 us; speedup 1.0000x reference)
//
#include <hip/hip_runtime.h>
#include <cstdint>

#define DEV __device__ __forceinline__

typedef __bf16 bf16x4 __attribute__((ext_vector_type(4)));
typedef __bf16 bf16x8 __attribute__((ext_vector_type(8)));
typedef float  floatx2 __attribute__((ext_vector_type(2)));
typedef float  floatx4 __attribute__((ext_vector_type(4)));
typedef float  floatx16 __attribute__((ext_vector_type(16)));
typedef unsigned uint4v __attribute__((ext_vector_type(4)));

constexpr int BB = 8, NSEQ = 1024, DMODEL = 768, NH = 12, HD = 64;
constexpr int MTOK = BB * NSEQ;   // 8192 tokens
constexpr int NQKV = 3 * DMODEL;  // 2304
constexpr float CS = 0.18033688011112042f;  // (1/sqrt(64)) * log2(e), folded into Q

DEV void async_copy16(void* lds, const void* g) {
    // global -> LDS direct copy, 16B/lane. LDS dest must be wave-base + lane*16.
    __builtin_amdgcn_global_load_lds(
        (__attribute__((address_space(1))) void*)(const_cast<void*>(g)),
        (__attribute__((address_space(3))) void*)lds,
        16, 0, 0);
}

DEV floatx4 mfma16x32(bf16x8 a, bf16x8 b, floatx4 c) {
    return __builtin_amdgcn_mfma_f32_16x16x32_bf16(a, b, c, 0, 0, 0);
}
DEV floatx16 mfma32x16(bf16x8 a, bf16x8 b, floatx16 c) {
    return __builtin_amdgcn_mfma_f32_32x32x16_bf16(a, b, c, 0, 0, 0);
}
DEV unsigned cvtpk(float a, float b) {
    unsigned r;
    asm("v_cvt_pk_bf16_f32 %0, %1, %2" : "=v"(r) : "v"(a), "v"(b));
    return r;
}
DEV void swap32(unsigned& x, unsigned& y) {
    // x' = {x[0:31], y[0:31]}, y' = {x[32:63], y[32:63]} (lane-half exchange)
    asm("v_permlane32_swap_b32 %0, %1" : "+v"(x), "+v"(y));
}

// 32x32x16 fragment-linear layouts (element indices), bh = b*12+h, b5 = lane>>5, l5 = lane&31:
//  QF (B-op): idx = ((bh*32 + qt)*4 + kfi)*512 + lane*8 + j
//  KF (A-op): idx = ((bh*32 + c)*4 + kfi)*512 + lane*8 + j          (chunk c of 32 keys)
//  VF (A-op): idx = ((bh*32 + c)*4 + kc*2 + mg)*512 + lane*8 + j
// All attention loads: base + lane*16B, perfectly coalesced, L2-resident (XCD-pinned).

// ---------------- fused prep: x->bf16 | W transpose->bf16 | bias concat ----------------
__global__ __launch_bounds__(256) void k_prep(const float* __restrict__ x,
                                              __bf16* __restrict__ xb,
                                              const float* __restrict__ Wq,
                                              const float* __restrict__ Wk,
                                              const float* __restrict__ Wv,
                                              const float* __restrict__ Wo,
                                              __bf16* __restrict__ wtqkv,
                                              __bf16* __restrict__ wto,
                                              const float* __restrict__ bq,
                                              const float* __restrict__ bk,
                                              const float* __restrict__ bv,
                                              float* __restrict__ bqkv) {
    __shared__ float tile[32][33];
    int bid = blockIdx.x, t = threadIdx.x;
    if (bid < 6144) {                       // x fp32 -> bf16, 4 elem/thread
        int i = (bid * 256 + t) * 4;
        float4 v = *(const float4*)(x + i);
        bf16x4 o;
        o[0] = (__bf16)v.x; o[1] = (__bf16)v.y; o[2] = (__bf16)v.z; o[3] = (__bf16)v.w;
        *(bf16x4*)(xb + i) = o;
    } else if (bid < 8448) {                // W [K,N] -> Wt [N,K] bf16
        int idx = bid - 6144;
        int z = idx / 576, rem = idx % 576;
        int k0 = (rem % 24) * 32, n0 = (rem / 24) * 32;
        const float* W = (z == 0) ? Wq : (z == 1) ? Wk : (z == 2) ? Wv : Wo;
        int tx = t & 31, ty = t >> 5;
#pragma unroll
        for (int p = 0; p < 4; p++)
            tile[ty + 8 * p][tx] = W[(size_t)(k0 + ty + 8 * p) * 768 + n0 + tx];
        __syncthreads();
        __bf16* out = (z < 3) ? (wtqkv + (size_t)z * 768 * 768) : wto;
#pragma unroll
        for (int p = 0; p < 4; p++)
            out[(size_t)(n0 + ty + 8 * p) * 768 + k0 + tx] = (__bf16)tile[tx][ty + 8 * p];
    } else {                                // bias concat
        int i = (bid - 8448) * 256 + t;
        if (i < 768) bqkv[i] = bq[i];
        else if (i < 1536) bqkv[i] = bk[i - 768];
        else bqkv[i] = bv[i - 1536];
    }
}

// ---------------- QKV GEMM: 2-slot double buffer, counted vmcnt, 2 blocks/CU ----------------
// (R6-verified; unchanged)
__global__ __launch_bounds__(256) void k_qkv(const __bf16* __restrict__ A,
                                             const __bf16* __restrict__ Bt,
                                             const float* __restrict__ bias,
                                             __bf16* __restrict__ qfb,
                                             __bf16* __restrict__ kfb,
                                             __bf16* __restrict__ vfb) {
    constexpr int SLOT = 16384;            // elems: As 128*64 + Bs 128*64 (32KB)
    __shared__ __align__(16) __bf16 lds[2 * SLOT];   // 64 KB
    int t = threadIdx.x, lane = t & 63, w = t >> 6;
    int quad = lane >> 4, n16 = lane & 15;
    int wm = w & 1, wn = w >> 1;           // 2M x 2N wave grid
    int m0 = blockIdx.x * 128, n0 = blockIdx.y * 128;
    floatx4 acc[4][4] = {};

    auto stage_tile = [&](__bf16* slot, int k0) {
        __bf16* As_ = slot;
        __bf16* Bs_ = slot + 8192;
#pragma unroll
        for (int i = 0; i < 4; i++) {      // A tile 128x64 (16KB): 4 insts
            int off = t + i * 256;
            int row = off >> 3, pc = off & 7;
            int c = pc ^ (row & 7);
            async_copy16(&As_[row * 64 + pc * 8],
                         &A[(size_t)(m0 + row) * 768 + k0 + c * 8]);
        }
#pragma unroll
        for (int i = 0; i < 4; i++) {      // B tile 128x64 (16KB): 4 insts
            int off = t + i * 256;
            int row = off >> 3, pc = off & 7;
            int c = pc ^ (row & 7);
            async_copy16(&Bs_[row * 64 + pc * 8],
                         &Bt[(size_t)(n0 + row) * 768 + k0 + c * 8]);
        }
    };

    stage_tile(lds, 0);                    // tile 0 in flight (8 loads)

#pragma unroll
    for (int kt = 0; kt < 12; kt++) {
        __bf16* As_ = lds + (kt & 1) * SLOT;
        __bf16* Bs_ = As_ + 8192;

        if (kt + 1 < 12) stage_tile(lds + ((kt + 1) & 1) * SLOT, (kt + 1) * 64);
        __builtin_amdgcn_sched_barrier(0);
        if (kt + 1 < 12) {
            // B1: outstanding = 8 (tile kt) + 8 (tile kt+1); wait to 8 -> tile kt
            // retired (in-order). Every wave does this BEFORE the barrier -> published.
            asm volatile("s_waitcnt vmcnt(8)\n\ts_barrier" ::: "memory");
        } else {
            asm volatile("s_waitcnt vmcnt(0)\n\ts_barrier" ::: "memory");
        }
        __builtin_amdgcn_sched_barrier(0);

#pragma unroll
        for (int kfi = 0; kfi < 2; kfi++) {
            bf16x8 a[4], bfr[4];
#pragma unroll
            for (int rt = 0; rt < 4; rt++) {
                int row = wm * 64 + rt * 16 + n16;
                a[rt] = *(const bf16x8*)&As_[row * 64 + ((quad + 4 * kfi) ^ (row & 7)) * 8];
            }
#pragma unroll
            for (int ct = 0; ct < 4; ct++) {
                int row = wn * 64 + ct * 16 + n16;
                bfr[ct] = *(const bf16x8*)&Bs_[row * 64 + ((quad + 4 * kfi) ^ (row & 7)) * 8];
            }
            __builtin_amdgcn_s_setprio(1);
#pragma unroll
            for (int rt = 0; rt < 4; rt++)
#pragma unroll
                for (int ct = 0; ct < 4; ct++)
                    acc[rt][ct] = mfma16x32(a[rt], bfr[ct], acc[rt][ct]);
            __builtin_amdgcn_s_setprio(0);
        }

        if (kt + 1 < 12) {
            __builtin_amdgcn_sched_barrier(0);
            // B2: all waves' ds_reads of slot cur complete -> overwritable next iter.
            asm volatile("s_barrier" ::: "memory");
            __builtin_amdgcn_sched_barrier(0);
        }
    }

    // epilogue: C/D layout col=lane&15, row=quad*4+reg. Zone is block-uniform.
    if (n0 >= 1536) {
        // V zone -> VF (A-operand of 32x32x16 PV)
#pragma unroll
        for (int ct = 0; ct < 4; ct++) {
            int col = n0 + wn * 64 + ct * 16 + n16;
            float bs = bias[col];
            int cz = col - 1536;
            int hh = cz >> 6, hd = cz & 63;
            int mg = hd >> 5, l5v = hd & 31;
#pragma unroll
            for (int rt = 0; rt < 4; rt++) {
                int row0 = m0 + wm * 64 + rt * 16 + quad * 4;
                int bb = row0 >> 10, key = row0 & 1023;
                int iw = key >> 7, w_ = (key >> 5) & 3, kc = (key >> 4) & 1;
                int b5v = (key >> 3) & 1, j0 = key & 7;  // +r stays in octet (quad*4 base)
                bf16x4 pk;
#pragma unroll
                for (int r = 0; r < 4; r++) pk[r] = (__bf16)(acc[rt][ct][r] + bs);
                size_t idx = (((((size_t)(bb * 12 + hh) * 8 + iw) * 4 + w_) * 2 + kc) * 2 + mg) * 512
                             + (size_t)(b5v * 32 + l5v) * 8 + j0;
                *(bf16x4*)&vfb[idx] = pk;
            }
        }
    } else {
        __bf16* dst = (n0 < 768) ? qfb : kfb;
        float mult = (n0 < 768) ? CS : 1.0f;
        bool isQ = (n0 < 768);
        int cofs = isQ ? 0 : 768;
#pragma unroll
        for (int ct = 0; ct < 4; ct++) {
            int col = n0 + wn * 64 + ct * 16 + n16;
            float bs = bias[col];
            int cz = col - cofs;
            int hh = cz >> 6, hd = cz & 63;
            int kfi = hd >> 4, b5v = (hd >> 3) & 1, j = hd & 7;
#pragma unroll
            for (int rt = 0; rt < 4; rt++) {
                int row0 = m0 + wm * 64 + rt * 16 + quad * 4;
                int bb = row0 >> 10, q10 = row0 & 1023;
                size_t idx;
                if (isQ) {
                    int qt = q10 >> 5, l5v = q10 & 31;  // l5v+r no carry (quad*4 base)
                    idx = (((size_t)(bb * 12 + hh) * 32 + qt) * 4 + kfi) * 512
                          + (size_t)(b5v * 32 + l5v) * 8 + j;
                } else {
                    int iw = q10 >> 7, w_ = (q10 >> 5) & 3, l5v = q10 & 31;
                    idx = ((((size_t)(bb * 12 + hh) * 8 + iw) * 4 + w_) * 4 + kfi) * 512
                          + (size_t)(b5v * 32 + l5v) * 8 + j;
                }
#pragma unroll
                for (int r = 0; r < 4; r++)
                    dst[idx + (size_t)r * 8] = (__bf16)((acc[rt][ct][r] + bs) * mult);
            }
        }
    }
}

// ---------------- O-projection: same 2-slot counted-vmcnt structure, BN=64 ----------------
// (R6-verified; unchanged)
__global__ __launch_bounds__(256) void k_oproj(const __bf16* __restrict__ A,
                                               const __bf16* __restrict__ Bt,
                                               const float* __restrict__ bias,
                                               float* __restrict__ C) {
    constexpr int SLOT = 12288;            // elems: As 128*64 + Bs 64*64 (24KB)
    __shared__ __align__(16) __bf16 lds[2 * SLOT];   // 48 KB
    int t = threadIdx.x, lane = t & 63, w = t >> 6;
    int quad = lane >> 4, n16 = lane & 15;
    int wm = w & 1, wn = w >> 1;
    int m0 = blockIdx.x * 128, n0 = blockIdx.y * 64;
    floatx4 acc[4][2] = {};

    auto stage_tile = [&](__bf16* slot, int k0) {
        __bf16* As_ = slot;
        __bf16* Bs_ = slot + 8192;
#pragma unroll
        for (int i = 0; i < 4; i++) {      // A tile 128x64 (16KB): 4 insts
            int off = t + i * 256;
            int row = off >> 3, pc = off & 7;
            int c = pc ^ (row & 7);
            async_copy16(&As_[row * 64 + pc * 8],
                         &A[(size_t)(m0 + row) * 768 + k0 + c * 8]);
        }
#pragma unroll
        for (int i = 0; i < 2; i++) {      // B tile 64x64 (8KB): 2 insts
            int off = t + i * 256;
            int row = off >> 3, pc = off & 7;
            int c = pc ^ (row & 7);
            async_copy16(&Bs_[row * 64 + pc * 8],
                         &Bt[(size_t)(n0 + row) * 768 + k0 + c * 8]);
        }
    };

    stage_tile(lds, 0);

#pragma unroll
    for (int kt = 0; kt < 12; kt++) {
        __bf16* As_ = lds + (kt & 1) * SLOT;
        __bf16* Bs_ = As_ + 8192;

        if (kt + 1 < 12) stage_tile(lds + ((kt + 1) & 1) * SLOT, (kt + 1) * 64);
        __builtin_amdgcn_sched_barrier(0);
        if (kt + 1 < 12) {
            asm volatile("s_waitcnt vmcnt(6)\n\ts_barrier" ::: "memory");
        } else {
            asm volatile("s_waitcnt vmcnt(0)\n\ts_barrier" ::: "memory");
        }
        __builtin_amdgcn_sched_barrier(0);

#pragma unroll
        for (int kfi = 0; kfi < 2; kfi++) {
            bf16x8 a[4], bfr[2];
#pragma unroll
            for (int rt = 0; rt < 4; rt++) {
                int row = wm * 64 + rt * 16 + n16;
                a[rt] = *(const bf16x8*)&As_[row * 64 + ((quad + 4 * kfi) ^ (row & 7)) * 8];
            }
#pragma unroll
            for (int ct = 0; ct < 2; ct++) {
                int row = wn * 32 + ct * 16 + n16;
                bfr[ct] = *(const bf16x8*)&Bs_[row * 64 + ((quad + 4 * kfi) ^ (row & 7)) * 8];
            }
            __builtin_amdgcn_s_setprio(1);
#pragma unroll
            for (int rt = 0; rt < 4; rt++)
#pragma unroll
                for (int ct = 0; ct < 2; ct++)
                    acc[rt][ct] = mfma16x32(a[rt], bfr[ct], acc[rt][ct]);
            __builtin_amdgcn_s_setprio(0);
        }

        if (kt + 1 < 12) {
            __builtin_amdgcn_sched_barrier(0);
            asm volatile("s_barrier" ::: "memory");
            __builtin_amdgcn_sched_barrier(0);
        }
    }

#pragma unroll
    for (int ct = 0; ct < 2; ct++) {
        int col = n0 + wn * 32 + ct * 16 + n16;
        float bs = bias[col];
#pragma unroll
        for (int rt = 0; rt < 4; rt++) {
#pragma unroll
            for (int r = 0; r < 4; r++) {
                int row = m0 + wm * 64 + rt * 16 + quad * 4 + r;
                C[(size_t)row * DMODEL + col] = acc[rt][ct][r] + bs;
            }
        }
    }
}

// ---------------- flash attention: 2 q-tiles per wave (dual-strand ILP) ----------------
// R10: R6-R9 showed ~42us invariant across four attn structures (epilogue, V-dbuf,
// L2-BW fixes all null) -> bottleneck is the per-wave serial chain (QK mfma chain ->
// exp2 -> pack -> PV chain, ~600cy latency per chunk) with too little TLP to hide it.
// Fix: each wave runs TWO independent q-tiles against the shared K/V registers --
// two strands interleave in each other's stall slots, and K/V loads amortize 2x.
// Block = 2 waves (128 thr); wave w owns qt = qb*4 + w*2 + {0,1}. Grid 768 as before.
// Per-chunk math/store = R8-verified, duplicated for qt1 (Q offset +4*512).
__global__ __launch_bounds__(128, 2) void k_attn(const __bf16* __restrict__ QF,
                                                 const __bf16* __restrict__ KF,
                                                 const __bf16* __restrict__ VF,
                                                 __bf16* __restrict__ ctx) {
    int t = threadIdx.x, lane = t & 63, w = t >> 6;   // w in {0,1}
    int l5 = lane & 31, b5 = lane >> 5;
    int id = blockIdx.x;
    int bB = id & 7;
    int seq = id >> 3;                    // [0,96)
    int h = seq % 12;
    int qb = seq / 12;                    // [0,8)
    int qt0 = qb * 4 + w * 2;             // this wave: q-tiles qt0, qt0+1
    int bh = bB * NH + h;

    // Q fragments for both q-tiles (qt+1 offset = 4*512 in QF)
    bf16x8 qf0[4], qf1[4];
    {
        const __bf16* qp = QF + ((size_t)(bh * 32 + qt0) * 4) * 512 + lane * 8;
#pragma unroll
        for (int kfi = 0; kfi < 4; kfi++) {
            qf0[kfi] = *(const bf16x8*)(qp + kfi * 512);
            qf1[kfi] = *(const bf16x8*)(qp + (4 + kfi) * 512);
        }
    }
    const __bf16* kp = KF + (size_t)(bh * 32) * 2048 + lane * 8;
    const __bf16* vp = VF + (size_t)(bh * 32) * 2048 + lane * 8;

    floatx16 acc0[2] = {}, acc1[2] = {};  // O^T per q-tile: [mg]
    floatx2 rsa = {0.f, 0.f}, rsb = {0.f, 0.f};
    float pma = 0.f, pmb = 0.f;

    auto compute = [&](bf16x8 (&kf)[4], bf16x8 (&vf)[4]) {
        // two independent QK chains -- interleave in each other's latency
        floatx16 s0 = {}, s1 = {};
#pragma unroll
        for (int kfi = 0; kfi < 4; kfi++)
            s0 = mfma32x16(kf[kfi], qf0[kfi], s0);
#pragma unroll
        for (int kfi = 0; kfi < 4; kfi++)
            s1 = mfma32x16(kf[kfi], qf1[kfi], s1);

        {   // strand 0: softmax + PV for qt0
            float p[16];
#pragma unroll
            for (int r = 0; r < 16; r++)
                p[r] = __builtin_amdgcn_exp2f(s0[r]);
#pragma unroll
            for (int r = 0; r < 16; r += 2) {
                floatx2 pp = {p[r], p[r + 1]};
                rsa += pp;
                pma = fmaxf(fmaxf(p[r], p[r + 1]), pma);
            }
            unsigned x0 = cvtpk(p[0], p[1]),   y0 = cvtpk(p[4], p[5]);
            unsigned x1 = cvtpk(p[2], p[3]),   y1 = cvtpk(p[6], p[7]);
            unsigned x2 = cvtpk(p[8], p[9]),   y2 = cvtpk(p[12], p[13]);
            unsigned x3 = cvtpk(p[10], p[11]), y3 = cvtpk(p[14], p[15]);
            swap32(x0, y0); swap32(x1, y1); swap32(x2, y2); swap32(x3, y3);
            uint4v pa = {x0, x1, y0, y1};
            uint4v pbv = {x2, x3, y2, y3};
            bf16x8 P0 = __builtin_bit_cast(bf16x8, pa);
            bf16x8 P1 = __builtin_bit_cast(bf16x8, pbv);
            acc0[0] = mfma32x16(vf[0], P0, acc0[0]);
            acc0[1] = mfma32x16(vf[1], P0, acc0[1]);
            acc0[0] = mfma32x16(vf[2], P1, acc0[0]);
            acc0[1] = mfma32x16(vf[3], P1, acc0[1]);
        }
        {   // strand 1: softmax + PV for qt1
            float p[16];
#pragma unroll
            for (int r = 0; r < 16; r++)
                p[r] = __builtin_amdgcn_exp2f(s1[r]);
#pragma unroll
            for (int r = 0; r < 16; r += 2) {
                floatx2 pp = {p[r], p[r + 1]};
                rsb += pp;
                pmb = fmaxf(fmaxf(p[r], p[r + 1]), pmb);
            }
            unsigned x0 = cvtpk(p[0], p[1]),   y0 = cvtpk(p[4], p[5]);
            unsigned x1 = cvtpk(p[2], p[3]),   y1 = cvtpk(p[6], p[7]);
            unsigned x2 = cvtpk(p[8], p[9]),   y2 = cvtpk(p[12], p[13]);
            unsigned x3 = cvtpk(p[10], p[11]), y3 = cvtpk(p[14], p[15]);
            swap32(x0, y0); swap32(x1, y1); swap32(x2, y2); swap32(x3, y3);
            uint4v pa = {x0, x1, y0, y1};
            uint4v pbv = {x2, x3, y2, y3};
            bf16x8 P0 = __builtin_bit_cast(bf16x8, pa);
            bf16x8 P1 = __builtin_bit_cast(bf16x8, pbv);
            acc1[0] = mfma32x16(vf[0], P0, acc1[0]);
            acc1[1] = mfma32x16(vf[1], P0, acc1[1]);
            acc1[0] = mfma32x16(vf[2], P1, acc1[0]);
            acc1[1] = mfma32x16(vf[3], P1, acc1[1]);
        }
    };

    // software pipeline over 32 chunks: K and V double-buffered (R8-proven), shared
    // by both strands.
    bf16x8 ka[4], kb[4], va[4], vb[4];
#pragma unroll
    for (int f = 0; f < 4; f++) ka[f] = *(const bf16x8*)(kp + f * 512);
#pragma unroll
    for (int f = 0; f < 4; f++) va[f] = *(const bf16x8*)(vp + f * 512);
    kp += 2048; vp += 2048;

    for (int c = 0; c < 32; c += 2) {
#pragma unroll
        for (int f = 0; f < 4; f++) kb[f] = *(const bf16x8*)(kp + f * 512);
#pragma unroll
        for (int f = 0; f < 4; f++) vb[f] = *(const bf16x8*)(vp + f * 512);
        kp += 2048; vp += 2048;
        compute(ka, va);
        if (c < 30) {
#pragma unroll
            for (int f = 0; f < 4; f++) ka[f] = *(const bf16x8*)(kp + f * 512);
#pragma unroll
            for (int f = 0; f < 4; f++) va[f] = *(const bf16x8*)(vp + f * 512);
            kp += 2048; vp += 2048;
        }
        compute(kb, vb);
    }

    // per-strand quiet-softmax finalize + direct store (R8-verified formulas)
    float rs0 = rsa[0] + rsa[1];
    rs0 += __shfl_xor(rs0, 32);
    pma = fmaxf(pma, __shfl_xor(pma, 32));
    float invd0 = 1.f / (pma + rs0);
    float rs1 = rsb[0] + rsb[1];
    rs1 += __shfl_xor(rs1, 32);
    pmb = fmaxf(pmb, __shfl_xor(pmb, 32));
    float invd1 = 1.f / (pmb + rs1);

    __bf16* dst0 = ctx + ((size_t)(bB * NSEQ) + qt0 * 32 + l5) * DMODEL + h * 64;
    __bf16* dst1 = dst0 + (size_t)32 * DMODEL;   // qt0+1
#pragma unroll
    for (int mg = 0; mg < 2; mg++)
#pragma unroll
        for (int rq = 0; rq < 4; rq++) {
            bf16x4 o0, o1;
#pragma unroll
            for (int e = 0; e < 4; e++) {
                o0[e] = (__bf16)(acc0[mg][rq * 4 + e] * invd0);
                o1[e] = (__bf16)(acc1[mg][rq * 4 + e] * invd1);
            }
            *(bf16x4*)(dst0 + mg * 32 + rq * 8 + b5 * 4) = o0;
            *(bf16x4*)(dst1 + mg * 32 + rq * 8 + b5 * 4) = o1;
        }
}

extern "C" void kernel_launch(void* const* d_in, const int* in_sizes, int n_in,
                              void* d_out, int out_size, void* d_ws, size_t ws_size,
                              hipStream_t stream) {
    (void)in_sizes; (void)n_in; (void)out_size;
    const float* x  = (const float*)d_in[0];
    const float* Wq = (const float*)d_in[1];
    const float* bq = (const float*)d_in[2];
    const float* Wk = (const float*)d_in[3];
    const float* bk = (const float*)d_in[4];
    const float* Wv = (const float*)d_in[5];
    const float* bv = (const float*)d_in[6];
    const float* Wo = (const float*)d_in[7];
    const float* bo = (const float*)d_in[8];
    float* out = (float*)d_out;

    char* ws = (char*)d_ws;
    size_t off = 0;
    auto alloc = [&](size_t bytes) {
        void* p = ws + off;
        off += (bytes + 255) & ~(size_t)255;
        return p;
    };
    __bf16* xb    = (__bf16*)alloc((size_t)MTOK * DMODEL * 2);   // 12.6 MB (reused as ctx)
    __bf16* wtqkv = (__bf16*)alloc((size_t)NQKV * DMODEL * 2);   // 3.5 MB
    __bf16* wto   = (__bf16*)alloc((size_t)DMODEL * DMODEL * 2); // 1.2 MB
    float*  bqkv  = (float*)alloc((size_t)NQKV * 4);
    __bf16* qfb   = (__bf16*)alloc((size_t)MTOK * DMODEL * 2);   // 12.6 MB frag-linear Q
    __bf16* kfb   = (__bf16*)alloc((size_t)MTOK * DMODEL * 2);   // 12.6 MB frag-linear K
    __bf16* vfb   = (__bf16*)alloc((size_t)MTOK * DMODEL * 2);   // 12.6 MB frag-linear V
    if (off > ws_size) return;  // workspace too small -> visible failure
    __bf16* ctx = xb;  // xb dead after QKV GEMM

    k_prep<<<dim3(8457), dim3(256), 0, stream>>>(x, xb, Wq, Wk, Wv, Wo, wtqkv, wto,
                                                 bq, bk, bv, bqkv);
    k_qkv<<<dim3(64, 18), dim3(256), 0, stream>>>(xb, wtqkv, bqkv, qfb, kfb, vfb);
    k_attn<<<dim3(768), dim3(128), 0, stream>>>(qfb, kfb, vfb, ctx);
    k_oproj<<<dim3(64, 12), dim3(256), 0, stream>>>(ctx, wto, bo, out);
}

// Round 11
// 175.990 us; speedup vs baseline: 1.0396x; 1.0396x over previous
//
#include <hip/hip_runtime.h>
#include <cstdint>

#define DEV __device__ __forceinline__

typedef __bf16 bf16x4 __attribute__((ext_vector_type(4)));
typedef __bf16 bf16x8 __attribute__((ext_vector_type(8)));
typedef float  floatx2 __attribute__((ext_vector_type(2)));
typedef float  floatx4 __attribute__((ext_vector_type(4)));
typedef float  floatx16 __attribute__((ext_vector_type(16)));
typedef unsigned uint4v __attribute__((ext_vector_type(4)));

constexpr int BB = 8, NSEQ = 1024, DMODEL = 768, NH = 12, HD = 64;
constexpr int MTOK = BB * NSEQ;   // 8192 tokens
constexpr int NQKV = 3 * DMODEL;  // 2304
constexpr float CS = 0.18033688011112042f;  // (1/sqrt(64)) * log2(e), folded into Q

DEV void async_copy16(void* lds, const void* g) {
    // global -> LDS direct copy, 16B/lane. LDS dest must be wave-base + lane*16.
    __builtin_amdgcn_global_load_lds(
        (__attribute__((address_space(1))) void*)(const_cast<void*>(g)),
        (__attribute__((address_space(3))) void*)lds,
        16, 0, 0);
}

DEV floatx4 mfma16x32(bf16x8 a, bf16x8 b, floatx4 c) {
    return __builtin_amdgcn_mfma_f32_16x16x32_bf16(a, b, c, 0, 0, 0);
}
DEV floatx16 mfma32x16(bf16x8 a, bf16x8 b, floatx16 c) {
    return __builtin_amdgcn_mfma_f32_32x32x16_bf16(a, b, c, 0, 0, 0);
}
DEV unsigned cvtpk(float a, float b) {
    unsigned r;
    asm("v_cvt_pk_bf16_f32 %0, %1, %2" : "=v"(r) : "v"(a), "v"(b));
    return r;
}
DEV void swap32(unsigned& x, unsigned& y) {
    // x' = {x[0:31], y[0:31]}, y' = {x[32:63], y[32:63]} (lane-half exchange)
    asm("v_permlane32_swap_b32 %0, %1" : "+v"(x), "+v"(y));
}

// 32x32x16 fragment-linear layouts (element indices), bh = b*12+h, b5 = lane>>5, l5 = lane&31:
//  QF (B-op): idx = ((bh*32 + qt)*4 + kfi)*512 + lane*8 + j
//  KF (A-op): idx = ((bh*32 + c)*4 + kfi)*512 + lane*8 + j          (chunk c of 32 keys)
//  VF (A-op): idx = ((bh*32 + c)*4 + kc*2 + mg)*512 + lane*8 + j
// All attention loads: base + lane*16B, perfectly coalesced, L2-resident (XCD-pinned).

// ---------------- fused prep: x->bf16 | W transpose->bf16 | bias concat ----------------
__global__ __launch_bounds__(256) void k_prep(const float* __restrict__ x,
                                              __bf16* __restrict__ xb,
                                              const float* __restrict__ Wq,
                                              const float* __restrict__ Wk,
                                              const float* __restrict__ Wv,
                                              const float* __restrict__ Wo,
                                              __bf16* __restrict__ wtqkv,
                                              __bf16* __restrict__ wto,
                                              const float* __restrict__ bq,
                                              const float* __restrict__ bk,
                                              const float* __restrict__ bv,
                                              float* __restrict__ bqkv) {
    __shared__ float tile[32][33];
    int bid = blockIdx.x, t = threadIdx.x;
    if (bid < 6144) {                       // x fp32 -> bf16, 4 elem/thread
        int i = (bid * 256 + t) * 4;
        float4 v = *(const float4*)(x + i);
        bf16x4 o;
        o[0] = (__bf16)v.x; o[1] = (__bf16)v.y; o[2] = (__bf16)v.z; o[3] = (__bf16)v.w;
        *(bf16x4*)(xb + i) = o;
    } else if (bid < 8448) {                // W [K,N] -> Wt [N,K] bf16
        int idx = bid - 6144;
        int z = idx / 576, rem = idx % 576;
        int k0 = (rem % 24) * 32, n0 = (rem / 24) * 32;
        const float* W = (z == 0) ? Wq : (z == 1) ? Wk : (z == 2) ? Wv : Wo;
        int tx = t & 31, ty = t >> 5;
#pragma unroll
        for (int p = 0; p < 4; p++)
            tile[ty + 8 * p][tx] = W[(size_t)(k0 + ty + 8 * p) * 768 + n0 + tx];
        __syncthreads();
        __bf16* out = (z < 3) ? (wtqkv + (size_t)z * 768 * 768) : wto;
#pragma unroll
        for (int p = 0; p < 4; p++)
            out[(size_t)(n0 + ty + 8 * p) * 768 + k0 + tx] = (__bf16)tile[tx][ty + 8 * p];
    } else {                                // bias concat
        int i = (bid - 8448) * 256 + t;
        if (i < 768) bqkv[i] = bq[i];
        else if (i < 1536) bqkv[i] = bk[i - 768];
        else bqkv[i] = bv[i - 1536];
    }
}

// ---------------- QKV GEMM: 2-slot counted-vmcnt ring, BN=64, 3 blocks/CU ----------------
// R11: BN 128->64. Slot = As 128x64 (16KB) + Bs 64x64 (8KB) = 24KB; x2 = 48KB LDS
// -> 3 uncoupled blocks/CU (was 2), and grid 64x36 = 2304 = EXACTLY 3 rounds of 768
// concurrent blocks (tail 11% -> 0). Main loop is byte-identical to the R6-verified
// oproj loop (6 loads/tile -> steady vmcnt(6)); epilogue keeps the proven
// absolute-index formulas (col/row0-based), with ct<2 and wn*32.
__global__ __launch_bounds__(256) void k_qkv(const __bf16* __restrict__ A,
                                             const __bf16* __restrict__ Bt,
                                             const float* __restrict__ bias,
                                             __bf16* __restrict__ qfb,
                                             __bf16* __restrict__ kfb,
                                             __bf16* __restrict__ vfb) {
    constexpr int SLOT = 12288;            // elems: As 128*64 + Bs 64*64 (24KB)
    __shared__ __align__(16) __bf16 lds[2 * SLOT];   // 48 KB
    int t = threadIdx.x, lane = t & 63, w = t >> 6;
    int quad = lane >> 4, n16 = lane & 15;
    int wm = w & 1, wn = w >> 1;
    int m0 = blockIdx.x * 128, n0 = blockIdx.y * 64;
    floatx4 acc[4][2] = {};

    auto stage_tile = [&](__bf16* slot, int k0) {
        __bf16* As_ = slot;
        __bf16* Bs_ = slot + 8192;
#pragma unroll
        for (int i = 0; i < 4; i++) {      // A tile 128x64 (16KB): 4 insts
            int off = t + i * 256;
            int row = off >> 3, pc = off & 7;
            int c = pc ^ (row & 7);
            async_copy16(&As_[row * 64 + pc * 8],
                         &A[(size_t)(m0 + row) * 768 + k0 + c * 8]);
        }
#pragma unroll
        for (int i = 0; i < 2; i++) {      // B tile 64x64 (8KB): 2 insts
            int off = t + i * 256;
            int row = off >> 3, pc = off & 7;
            int c = pc ^ (row & 7);
            async_copy16(&Bs_[row * 64 + pc * 8],
                         &Bt[(size_t)(n0 + row) * 768 + k0 + c * 8]);
        }
    };

    stage_tile(lds, 0);

#pragma unroll
    for (int kt = 0; kt < 12; kt++) {
        __bf16* As_ = lds + (kt & 1) * SLOT;
        __bf16* Bs_ = As_ + 8192;

        if (kt + 1 < 12) stage_tile(lds + ((kt + 1) & 1) * SLOT, (kt + 1) * 64);
        __builtin_amdgcn_sched_barrier(0);
        if (kt + 1 < 12) {
            // B1: per-wave counted vmcnt BEFORE the barrier publishes tile kt.
            asm volatile("s_waitcnt vmcnt(6)\n\ts_barrier" ::: "memory");
        } else {
            asm volatile("s_waitcnt vmcnt(0)\n\ts_barrier" ::: "memory");
        }
        __builtin_amdgcn_sched_barrier(0);

#pragma unroll
        for (int kfi = 0; kfi < 2; kfi++) {
            bf16x8 a[4], bfr[2];
#pragma unroll
            for (int rt = 0; rt < 4; rt++) {
                int row = wm * 64 + rt * 16 + n16;
                a[rt] = *(const bf16x8*)&As_[row * 64 + ((quad + 4 * kfi) ^ (row & 7)) * 8];
            }
#pragma unroll
            for (int ct = 0; ct < 2; ct++) {
                int row = wn * 32 + ct * 16 + n16;
                bfr[ct] = *(const bf16x8*)&Bs_[row * 64 + ((quad + 4 * kfi) ^ (row & 7)) * 8];
            }
            __builtin_amdgcn_s_setprio(1);
#pragma unroll
            for (int rt = 0; rt < 4; rt++)
#pragma unroll
                for (int ct = 0; ct < 2; ct++)
                    acc[rt][ct] = mfma16x32(a[rt], bfr[ct], acc[rt][ct]);
            __builtin_amdgcn_s_setprio(0);
        }

        if (kt + 1 < 12) {
            __builtin_amdgcn_sched_barrier(0);
            // B2: all waves' ds_reads of slot cur complete -> overwritable next iter.
            asm volatile("s_barrier" ::: "memory");
            __builtin_amdgcn_sched_barrier(0);
        }
    }

    // epilogue: C/D layout col=lane&15, row=quad*4+reg. Zone is block-uniform
    // (64-wide tiles never straddle 768/1536 boundaries). Index math absolute.
    if (n0 >= 1536) {
        // V zone -> VF (A-operand of 32x32x16 PV)
#pragma unroll
        for (int ct = 0; ct < 2; ct++) {
            int col = n0 + wn * 32 + ct * 16 + n16;
            float bs = bias[col];
            int cz = col - 1536;
            int hh = cz >> 6, hd = cz & 63;
            int mg = hd >> 5, l5v = hd & 31;
#pragma unroll
            for (int rt = 0; rt < 4; rt++) {
                int row0 = m0 + wm * 64 + rt * 16 + quad * 4;
                int bb = row0 >> 10, key = row0 & 1023;
                int iw = key >> 7, w_ = (key >> 5) & 3, kc = (key >> 4) & 1;
                int b5v = (key >> 3) & 1, j0 = key & 7;  // +r stays in octet (quad*4 base)
                bf16x4 pk;
#pragma unroll
                for (int r = 0; r < 4; r++) pk[r] = (__bf16)(acc[rt][ct][r] + bs);
                size_t idx = (((((size_t)(bb * 12 + hh) * 8 + iw) * 4 + w_) * 2 + kc) * 2 + mg) * 512
                             + (size_t)(b5v * 32 + l5v) * 8 + j0;
                *(bf16x4*)&vfb[idx] = pk;
            }
        }
    } else {
        __bf16* dst = (n0 < 768) ? qfb : kfb;
        float mult = (n0 < 768) ? CS : 1.0f;
        bool isQ = (n0 < 768);
        int cofs = isQ ? 0 : 768;
#pragma unroll
        for (int ct = 0; ct < 2; ct++) {
            int col = n0 + wn * 32 + ct * 16 + n16;
            float bs = bias[col];
            int cz = col - cofs;
            int hh = cz >> 6, hd = cz & 63;
            int kfi = hd >> 4, b5v = (hd >> 3) & 1, j = hd & 7;
#pragma unroll
            for (int rt = 0; rt < 4; rt++) {
                int row0 = m0 + wm * 64 + rt * 16 + quad * 4;
                int bb = row0 >> 10, q10 = row0 & 1023;
                size_t idx;
                if (isQ) {
                    int qt = q10 >> 5, l5v = q10 & 31;  // l5v+r no carry (quad*4 base)
                    idx = (((size_t)(bb * 12 + hh) * 32 + qt) * 4 + kfi) * 512
                          + (size_t)(b5v * 32 + l5v) * 8 + j;
                } else {
                    int iw = q10 >> 7, w_ = (q10 >> 5) & 3, l5v = q10 & 31;
                    idx = ((((size_t)(bb * 12 + hh) * 8 + iw) * 4 + w_) * 4 + kfi) * 512
                          + (size_t)(b5v * 32 + l5v) * 8 + j;
                }
#pragma unroll
                for (int r = 0; r < 4; r++)
                    dst[idx + (size_t)r * 8] = (__bf16)((acc[rt][ct][r] + bs) * mult);
            }
        }
    }
}

// ---------------- O-projection: same 2-slot counted-vmcnt structure, BN=64 ----------------
// (R6-verified; unchanged)
__global__ __launch_bounds__(256) void k_oproj(const __bf16* __restrict__ A,
                                               const __bf16* __restrict__ Bt,
                                               const float* __restrict__ bias,
                                               float* __restrict__ C) {
    constexpr int SLOT = 12288;            // elems: As 128*64 + Bs 64*64 (24KB)
    __shared__ __align__(16) __bf16 lds[2 * SLOT];   // 48 KB
    int t = threadIdx.x, lane = t & 63, w = t >> 6;
    int quad = lane >> 4, n16 = lane & 15;
    int wm = w & 1, wn = w >> 1;
    int m0 = blockIdx.x * 128, n0 = blockIdx.y * 64;
    floatx4 acc[4][2] = {};

    auto stage_tile = [&](__bf16* slot, int k0) {
        __bf16* As_ = slot;
        __bf16* Bs_ = slot + 8192;
#pragma unroll
        for (int i = 0; i < 4; i++) {      // A tile 128x64 (16KB): 4 insts
            int off = t + i * 256;
            int row = off >> 3, pc = off & 7;
            int c = pc ^ (row & 7);
            async_copy16(&As_[row * 64 + pc * 8],
                         &A[(size_t)(m0 + row) * 768 + k0 + c * 8]);
        }
#pragma unroll
        for (int i = 0; i < 2; i++) {      // B tile 64x64 (8KB): 2 insts
            int off = t + i * 256;
            int row = off >> 3, pc = off & 7;
            int c = pc ^ (row & 7);
            async_copy16(&Bs_[row * 64 + pc * 8],
                         &Bt[(size_t)(n0 + row) * 768 + k0 + c * 8]);
        }
    };

    stage_tile(lds, 0);

#pragma unroll
    for (int kt = 0; kt < 12; kt++) {
        __bf16* As_ = lds + (kt & 1) * SLOT;
        __bf16* Bs_ = As_ + 8192;

        if (kt + 1 < 12) stage_tile(lds + ((kt + 1) & 1) * SLOT, (kt + 1) * 64);
        __builtin_amdgcn_sched_barrier(0);
        if (kt + 1 < 12) {
            asm volatile("s_waitcnt vmcnt(6)\n\ts_barrier" ::: "memory");
        } else {
            asm volatile("s_waitcnt vmcnt(0)\n\ts_barrier" ::: "memory");
        }
        __builtin_amdgcn_sched_barrier(0);

#pragma unroll
        for (int kfi = 0; kfi < 2; kfi++) {
            bf16x8 a[4], bfr[2];
#pragma unroll
            for (int rt = 0; rt < 4; rt++) {
                int row = wm * 64 + rt * 16 + n16;
                a[rt] = *(const bf16x8*)&As_[row * 64 + ((quad + 4 * kfi) ^ (row & 7)) * 8];
            }
#pragma unroll
            for (int ct = 0; ct < 2; ct++) {
                int row = wn * 32 + ct * 16 + n16;
                bfr[ct] = *(const bf16x8*)&Bs_[row * 64 + ((quad + 4 * kfi) ^ (row & 7)) * 8];
            }
            __builtin_amdgcn_s_setprio(1);
#pragma unroll
            for (int rt = 0; rt < 4; rt++)
#pragma unroll
                for (int ct = 0; ct < 2; ct++)
                    acc[rt][ct] = mfma16x32(a[rt], bfr[ct], acc[rt][ct]);
            __builtin_amdgcn_s_setprio(0);
        }

        if (kt + 1 < 12) {
            __builtin_amdgcn_sched_barrier(0);
            asm volatile("s_barrier" ::: "memory");
            __builtin_amdgcn_sched_barrier(0);
        }
    }

#pragma unroll
    for (int ct = 0; ct < 2; ct++) {
        int col = n0 + wn * 32 + ct * 16 + n16;
        float bs = bias[col];
#pragma unroll
        for (int rt = 0; rt < 4; rt++) {
#pragma unroll
            for (int r = 0; r < 4; r++) {
                int row = m0 + wm * 64 + rt * 16 + quad * 4 + r;
                C[(size_t)row * DMODEL + col] = acc[rt][ct][r] + bs;
            }
        }
    }
}

// ---------------- flash attention: wave-per-qtile, S-chain software pipeline ----------------
// R11: constant-TLP ILP. Grid 768 x 4 waves (3 waves/SIMD, as R8 -- R10's dual-strand
// halved TLP and was null). Per-wave, the per-chunk serial chain (chained QK MFMAs ->
// exp2 -> pack -> PV) is software-pipelined depth-1: QK(c) is issued BEFORE
// finish(c-1), so the matrix-pipe QK chain of chunk c overlaps the trans/VALU
// softmax + PV of chunk c-1. Two named register sets rotate (unroll-2, all
// compile-time indexing -- no scratch). Softmax identity + store = R8-verified.
__global__ __launch_bounds__(256) void k_attn(const __bf16* __restrict__ QF,
                                              const __bf16* __restrict__ KF,
                                              const __bf16* __restrict__ VF,
                                              __bf16* __restrict__ ctx) {
    int t = threadIdx.x, lane = t & 63, w = t >> 6;
    int l5 = lane & 31, b5 = lane >> 5;
    int id = blockIdx.x;
    int bB = id & 7;
    int seq = id >> 3;                    // [0,96)
    int h = seq % 12;
    int qb = seq / 12;                    // [0,8)
    int qt = qb * 4 + w;                  // [0,32): this wave's q-tile
    int bh = bB * NH + h;

    // Q fragments (B-operand), coalesced frag-linear loads
    bf16x8 qf[4];
    {
        const __bf16* qp = QF + ((size_t)(bh * 32 + qt) * 4) * 512 + lane * 8;
#pragma unroll
        for (int kfi = 0; kfi < 4; kfi++)
            qf[kfi] = *(const bf16x8*)(qp + kfi * 512);
    }
    const __bf16* kp = KF + (size_t)(bh * 32) * 2048 + lane * 8;
    const __bf16* vp = VF + (size_t)(bh * 32) * 2048 + lane * 8;

    floatx16 acc[2] = {};                 // O^T: [mg]; D row=hd_local, col=qrow
    floatx2 rs2 = {0.f, 0.f};
    float pm = 0.f;

    auto qk = [&](bf16x8 (&kf)[4]) {
        floatx16 s = {};
#pragma unroll
        for (int kfi = 0; kfi < 4; kfi++)
            s = mfma32x16(kf[kfi], qf[kfi], s);
        return s;
    };
    auto fin = [&](floatx16 s, bf16x8 (&vf)[4]) {
        float p[16];
#pragma unroll
        for (int r = 0; r < 16; r++)
            p[r] = __builtin_amdgcn_exp2f(s[r]);
#pragma unroll
        for (int r = 0; r < 16; r += 2) {
            floatx2 pp = {p[r], p[r + 1]};
            rs2 += pp;                              // v_pk_add_f32
            pm = fmaxf(fmaxf(p[r], p[r + 1]), pm);  // v_max3_f32
        }
        // kc0 (keys 0..15): words {x0,x1,y0,y1}; kc1 (keys 16..31): {x2,x3,y2,y3}
        unsigned x0 = cvtpk(p[0], p[1]),   y0 = cvtpk(p[4], p[5]);
        unsigned x1 = cvtpk(p[2], p[3]),   y1 = cvtpk(p[6], p[7]);
        unsigned x2 = cvtpk(p[8], p[9]),   y2 = cvtpk(p[12], p[13]);
        unsigned x3 = cvtpk(p[10], p[11]), y3 = cvtpk(p[14], p[15]);
        swap32(x0, y0); swap32(x1, y1); swap32(x2, y2); swap32(x3, y3);
        uint4v pa = {x0, x1, y0, y1};
        uint4v pbv = {x2, x3, y2, y3};
        bf16x8 P0 = __builtin_bit_cast(bf16x8, pa);
        bf16x8 P1 = __builtin_bit_cast(bf16x8, pbv);
        acc[0] = mfma32x16(vf[0], P0, acc[0]);   // kc0, mg0
        acc[1] = mfma32x16(vf[1], P0, acc[1]);   // kc0, mg1
        acc[0] = mfma32x16(vf[2], P1, acc[0]);   // kc1, mg0
        acc[1] = mfma32x16(vf[3], P1, acc[1]);   // kc1, mg1
    };

    // pipeline: s0/v0 hold chunk c-1's score-chain while chunk c's QK issues.
    bf16x8 k0[4], v0[4], k1[4], v1[4];
#pragma unroll
    for (int f = 0; f < 4; f++) k0[f] = *(const bf16x8*)(kp + f * 512);
#pragma unroll
    for (int f = 0; f < 4; f++) v0[f] = *(const bf16x8*)(vp + f * 512);
    kp += 2048; vp += 2048;
    floatx16 s0 = qk(k0);

    for (int c = 1; c < 31; c += 2) {
        // chunk c -> set 1; finish chunk c-1 under its QK chain
#pragma unroll
        for (int f = 0; f < 4; f++) k1[f] = *(const bf16x8*)(kp + f * 512);
#pragma unroll
        for (int f = 0; f < 4; f++) v1[f] = *(const bf16x8*)(vp + f * 512);
        kp += 2048; vp += 2048;
        floatx16 s1 = qk(k1);
        fin(s0, v0);
        // chunk c+1 -> set 0; finish chunk c under its QK chain
#pragma unroll
        for (int f = 0; f < 4; f++) k0[f] = *(const bf16x8*)(kp + f * 512);
#pragma unroll
        for (int f = 0; f < 4; f++) v0[f] = *(const bf16x8*)(vp + f * 512);
        kp += 2048; vp += 2048;
        s0 = qk(k0);
        fin(s1, v1);
    }
    // chunk 31 + drain
    {
#pragma unroll
        for (int f = 0; f < 4; f++) k1[f] = *(const bf16x8*)(kp + f * 512);
#pragma unroll
        for (int f = 0; f < 4; f++) v1[f] = *(const bf16x8*)(vp + f * 512);
        floatx16 s1 = qk(k1);
        fin(s0, v0);
        fin(s1, v1);
    }

    // rs/pm: lane-halves held disjoint keys of the same qrow -> one half-swap reduce
    float rs = rs2[0] + rs2[1];
    rs += __shfl_xor(rs, 32);
    pm = fmaxf(pm, __shfl_xor(pm, 32));
    float invd = 1.f / (pm + rs);

    // direct store: lane holds O^T[qrow=l5]; hd = mg*32 + rq*8 + b5*4 + e
    __bf16* dst = ctx + ((size_t)(bB * NSEQ) + qt * 32 + l5) * DMODEL + h * 64;
#pragma unroll
    for (int mg = 0; mg < 2; mg++)
#pragma unroll
        for (int rq = 0; rq < 4; rq++) {
            bf16x4 o;
#pragma unroll
            for (int e = 0; e < 4; e++)
                o[e] = (__bf16)(acc[mg][rq * 4 + e] * invd);
            *(bf16x4*)(dst + mg * 32 + rq * 8 + b5 * 4) = o;
        }
}

extern "C" void kernel_launch(void* const* d_in, const int* in_sizes, int n_in,
                              void* d_out, int out_size, void* d_ws, size_t ws_size,
                              hipStream_t stream) {
    (void)in_sizes; (void)n_in; (void)out_size;
    const float* x  = (const float*)d_in[0];
    const float* Wq = (const float*)d_in[1];
    const float* bq = (const float*)d_in[2];
    const float* Wk = (const float*)d_in[3];
    const float* bk = (const float*)d_in[4];
    const float* Wv = (const float*)d_in[5];
    const float* bv = (const float*)d_in[6];
    const float* Wo = (const float*)d_in[7];
    const float* bo = (const float*)d_in[8];
    float* out = (float*)d_out;

    char* ws = (char*)d_ws;
    size_t off = 0;
    auto alloc = [&](size_t bytes) {
        void* p = ws + off;
        off += (bytes + 255) & ~(size_t)255;
        return p;
    };
    __bf16* xb    = (__bf16*)alloc((size_t)MTOK * DMODEL * 2);   // 12.6 MB (reused as ctx)
    __bf16* wtqkv = (__bf16*)alloc((size_t)NQKV * DMODEL * 2);   // 3.5 MB
    __bf16* wto   = (__bf16*)alloc((size_t)DMODEL * DMODEL * 2); // 1.2 MB
    float*  bqkv  = (float*)alloc((size_t)NQKV * 4);
    __bf16* qfb   = (__bf16*)alloc((size_t)MTOK * DMODEL * 2);   // 12.6 MB frag-linear Q
    __bf16* kfb   = (__bf16*)alloc((size_t)MTOK * DMODEL * 2);   // 12.6 MB frag-linear K
    __bf16* vfb   = (__bf16*)alloc((size_t)MTOK * DMODEL * 2);   // 12.6 MB frag-linear V
    if (off > ws_size) return;  // workspace too small -> visible failure
    __bf16* ctx = xb;  // xb dead after QKV GEMM

    k_prep<<<dim3(8457), dim3(256), 0, stream>>>(x, xb, Wq, Wk, Wv, Wo, wtqkv, wto,
                                                 bq, bk, bv, bqkv);
    k_qkv<<<dim3(64, 36), dim3(256), 0, stream>>>(xb, wtqkv, bqkv, qfb, kfb, vfb);
    k_attn<<<dim3(768), dim3(256), 0, stream>>>(qfb, kfb, vfb, ctx);
    k_oproj<<<dim3(64, 12), dim3(256), 0, stream>>>(ctx, wto, bo, out);
}